// Round 9
// baseline (650.373 us; speedup 1.0000x reference)
//
#include <hip/hip_runtime.h>
#include <math.h>

#define B_ 64
#define T_ 1024
#define D_ 256
#define U_ 256

typedef __fp16   hf2_t __attribute__((ext_vector_type(2)));  // cvt_pkrtz ret type
typedef _Float16 f16x8 __attribute__((ext_vector_type(8)));
typedef float    f32x4 __attribute__((ext_vector_type(4)));

// ---------------------------------------------------------------------------
// branch-free fast tanh: tanh(x) = 1 - 2/(1 + e^{2x}). (validated R2/R3/R7/R8)
// ---------------------------------------------------------------------------
__device__ __forceinline__ float fast_tanh2(float x) {
    float e = __expf(2.0f * x);
    return 1.0f - 2.0f * __builtin_amdgcn_rcpf(e + 1.0f);
}

// ---------------------------------------------------------------------------
// R9: producer/consumer wave specialization. 64 blocks (1 batch), 8 waves.
//   Waves 0-3 (SCAN): 64 cols each (nt=4). Halves the R8 step's dominant
//     cost: per-CU LDS A-fragment traffic 64 -> 32 b128 instrs/step (R8's
//     8 waves each re-read the full 512B h as replicated fragments; step
//     stayed ~1170 cyc from R3->R8 because this, not the MFMA chain, is
//     the pole). MFMA issue also halves (1 wave x 32 mfma per SIMD).
//   Waves 4-7 (PRODUCER): hold W_xh fragments; between the SAME per-step
//     barriers they PACK the next inputs chunk, PROJECT next xw (4 mfma
//     per step-slice), dump finished h rows (row J-1 after barrier J-1),
//     and prefetch inputs. Boundary bulk work dissolves into the rhythm:
//     exactly 16 barriers/chunk on both paths.
//   wf[8][4] is a UNION: W_hh frags (scan) / W_xh frags (producer) in the
//     same 128 VGPRs -- key to fitting 2 waves/SIMD.
// All fragment lane mappings, swizzles, PACK, tanh are byte-identical to the
// R3/R7/R8 validated kernels; only wave roles / scheduling change.
// ---------------------------------------------------------------------------
#define CH_  16
#define NCH_ (T_ / CH_)
#define NT2_ 512

__global__ __launch_bounds__(NT2_) __attribute__((amdgpu_waves_per_eu(2, 2)))
void rnn_fused(const float* __restrict__ inputs,  // [B_, T_, D_]
               const float* __restrict__ W_xh,    // [D_, U_]
               const float* __restrict__ W_hh,    // [U_, U_]
               const float* __restrict__ b_h,     // [U_]
               float* __restrict__ out) {         // [B_, T_, U_] h out
    const int b    = (int)blockIdx.x;
    const int tid  = (int)threadIdx.x;
    const int w    = tid >> 6;                  // wave 0..7
    const int lane = tid & 63;
    const int g    = lane >> 4;                 // k/row group 0..3
    const int c    = lane & 15;                 // col within 16-tile
    const bool scanw   = (w < 4);
    const int  colbase = (w & 3) * 64;          // this wave's 64-col slice

    __shared__ float buf[2][CH_][U_];               // 32 KB xw in / h out
    __shared__ __align__(16) _Float16 hl[2][U_];    // 2 x 512 B h state
    __shared__ __align__(16) _Float16 Ax[CH_ * D_]; // 8 KB inputs chunk (f16,swz)

    // unified B-fragments: wf[kt][nt] elem j = Wsrc[kt*32+g*8+j][colbase+nt*16+c]
    const float* Wsrc = scanw ? W_hh : W_xh;
    f16x8 wf[8][4];
    #pragma unroll
    for (int kt = 0; kt < 8; ++kt) {
        #pragma unroll
        for (int nt = 0; nt < 4; ++nt) {
            f16x8 v;
            #pragma unroll
            for (int j = 0; j < 8; ++j)
                v[j] = (_Float16)Wsrc[(size_t)(kt * 32 + g * 8 + j) * U_
                                      + colbase + nt * 16 + c];
            wf[kt][nt] = v;
        }
    }
    float pbb0 = 0.f, pbb1 = 0.f, pbb2 = 0.f, pbb3 = 0.f;
    if (!scanw) {
        pbb0 = b_h[colbase + c];      pbb1 = b_h[colbase + 16 + c];
        pbb2 = b_h[colbase + 32 + c]; pbb3 = b_h[colbase + 48 + c];
    }

    if (tid < 128) ((float*)&hl[0][0])[tid] = 0.f;   // zero h (512 B)

    const float* ibase = inputs + (size_t)b * T_ * D_;
    float* gbase = out + (size_t)b * T_ * U_;
    char*  bufD  = (char*)&buf[0][0][0];

    // ---- producer lane constants
    const int pl = tid & 255;                    // producer flat lane 0..255
    const int srow = pl >> 5;                    // Ax staging row (q = pl)
    const int sk8b = (pl & 31) * 16;             // byte offset of k8 f16s
    char* const sdst0 = (char*)Ax + srow * 512 + (sk8b ^ ((srow & 7) << 4));
    char* const sdst1 = sdst0 + 4096;            // q = pl+256: row+8, same swz bit
    const int vbaseA = c * 512 + ((g * 16) ^ ((c & 7) << 4));  // Ax frag base

    float4 p0, p1, p2, p3;                       // inputs prefetch (chunk-long)
    f32x4 pacc0 = {0,0,0,0}, pacc1 = {0,0,0,0},  // PROJECT acc (chunk-long)
          pacc2 = {0,0,0,0}, pacc3 = {0,0,0,0};

#define PACK8(DST, F0, F1)                                                    \
    {                                                                         \
        union { hf2_t p[4]; f16x8 v; } u;                                     \
        u.p[0] = __builtin_amdgcn_cvt_pkrtz((F0).x, (F0).y);                  \
        u.p[1] = __builtin_amdgcn_cvt_pkrtz((F0).z, (F0).w);                  \
        u.p[2] = __builtin_amdgcn_cvt_pkrtz((F1).x, (F1).y);                  \
        u.p[3] = __builtin_amdgcn_cvt_pkrtz((F1).z, (F1).w);                  \
        *(f16x8*)(DST) = u.v;                                                 \
    }

#define MFMA16(A, BF, ACC) \
    ACC = __builtin_amdgcn_mfma_f32_16x16x32_f16((A), (BF), (ACC), 0, 0, 0)

#define BAR()                                                                 \
    asm volatile("s_waitcnt lgkmcnt(0)" ::: "memory");                        \
    __builtin_amdgcn_s_barrier();                                             \
    asm volatile("" ::: "memory");

    // ---- prologue -------------------------------------------------------
    if (!scanw) {   // stage inputs chunk 0 -> Ax
        float4 f0 = *(const float4*)&ibase[8 * pl];
        float4 f1 = *(const float4*)&ibase[8 * pl + 4];
        float4 f2 = *(const float4*)&ibase[8 * pl + 2048];
        float4 f3 = *(const float4*)&ibase[8 * pl + 2052];
        PACK8(sdst0, f0, f1)
        PACK8(sdst1, f2, f3)
    }
    __syncthreads();
    if (!scanw) {   // PROJECT chunk 0 -> buf[0]; prefetch inputs chunk 1
        #pragma unroll
        for (int kt = 0; kt < 8; ++kt) {
            f16x8 a = *(const f16x8*)((const char*)Ax + (vbaseA ^ (kt * 64)));
            MFMA16(a, wf[kt][0], pacc0); MFMA16(a, wf[kt][1], pacc1);
            MFMA16(a, wf[kt][2], pacc2); MFMA16(a, wf[kt][3], pacc3);
        }
        #pragma unroll
        for (int r = 0; r < 4; ++r) {
            float* row = &buf[0][g * 4 + r][colbase + c];
            row[0]  = pacc0[r] + pbb0;  row[16] = pacc1[r] + pbb1;
            row[32] = pacc2[r] + pbb2;  row[48] = pacc3[r] + pbb3;
        }
        pacc0 = f32x4{0,0,0,0}; pacc1 = f32x4{0,0,0,0};
        pacc2 = f32x4{0,0,0,0}; pacc3 = f32x4{0,0,0,0};
        const float* gs = ibase + (size_t)CH_ * D_;
        p0 = *(const float4*)&gs[8 * pl];        p1 = *(const float4*)&gs[8 * pl + 4];
        p2 = *(const float4*)&gs[8 * pl + 2048]; p3 = *(const float4*)&gs[8 * pl + 2052];
    }
    __syncthreads();

    // ---- scan-wave lane addresses
    const char* hrd = (const char*)&hl[0][0] + g * 16;        // A-read (+64*kt)
    char*       hwr = (char*)&hl[0][0] + colbase * 2 + 2 * c; // h-write (+nt*32)

    // consumer step J: reads hl[J&1] + buf[cur] row J; writes hl[(J&1)^1] + h
#define STEP(J)                                                               \
    {                                                                         \
        const int RD = ((J) & 1) * 512;                                       \
        const int WR = 512 - RD;                                              \
        char* bc = bufD + cur * 16384 + (J) * 1024 + (colbase + c) * 4;       \
        const float xw0 = *(const float*)(bc);                                \
        const float xw1 = *(const float*)(bc + 64);                           \
        const float xw2 = *(const float*)(bc + 128);                          \
        const float xw3 = *(const float*)(bc + 192);                          \
        f32x4 ca0={0,0,0,0}, ca1={0,0,0,0}, ca2={0,0,0,0}, ca3={0,0,0,0};     \
        f32x4 cb0={0,0,0,0}, cb1={0,0,0,0}, cb2={0,0,0,0}, cb3={0,0,0,0};     \
        _Pragma("unroll") for (int kt = 0; kt < 4; ++kt) {                    \
            f16x8 a = *(const f16x8*)(hrd + RD + 64 * kt);                    \
            MFMA16(a, wf[kt][0], ca0); MFMA16(a, wf[kt][1], ca1);             \
            MFMA16(a, wf[kt][2], ca2); MFMA16(a, wf[kt][3], ca3);             \
        }                                                                     \
        _Pragma("unroll") for (int kt = 4; kt < 8; ++kt) {                    \
            f16x8 a = *(const f16x8*)(hrd + RD + 64 * kt);                    \
            MFMA16(a, wf[kt][0], cb0); MFMA16(a, wf[kt][1], cb1);             \
            MFMA16(a, wf[kt][2], cb2); MFMA16(a, wf[kt][3], cb3);             \
        }                                                                     \
        const float h0 = fast_tanh2(ca0[0] + cb0[0] + xw0);                   \
        const float h1 = fast_tanh2(ca1[0] + cb1[0] + xw1);                   \
        const float h2 = fast_tanh2(ca2[0] + cb2[0] + xw2);                   \
        const float h3 = fast_tanh2(ca3[0] + cb3[0] + xw3);                   \
        if (g == 0) {                                                         \
            *(float*)(bc)       = h0;  *(float*)(bc + 64)  = h1;              \
            *(float*)(bc + 128) = h2;  *(float*)(bc + 192) = h3;              \
            *(_Float16*)(hwr + WR)      = (_Float16)h0;                       \
            *(_Float16*)(hwr + WR + 32) = (_Float16)h1;                       \
            *(_Float16*)(hwr + WR + 64) = (_Float16)h2;                       \
            *(_Float16*)(hwr + WR + 96) = (_Float16)h3;                       \
        }                                                                     \
        BAR()                                                                 \
    }

    // producer slice J (between the same barriers as STEP(J)):
    //  J=0: dump prev chunk row 15; PACK Ax(ch+1)
    //  J>=1: dump row J-1 of current chunk (finalized at barrier J-1)
    //  J=1..8: one kt of PROJECT(ch+1) into pacc
    //  J=9: write pacc+bias -> buf[1-cur]; re-zero pacc
    //  J=10: prefetch inputs chunk ch+2
#define SLICE(J)                                                              \
    {                                                                         \
        if ((J) == 0) {                                                       \
            if (ch > 0) {                                                     \
                float v = *(const float*)(bufD + (1 - cur) * 16384            \
                                          + 15 * 1024 + 4 * pl);              \
                gbase[(size_t)(ch * 16 - 1) * 256 + pl] = v;                  \
            }                                                                 \
            if (ch + 1 < NCH_) { PACK8(sdst0, p0, p1) PACK8(sdst1, p2, p3) }  \
        } else {                                                              \
            float v = *(const float*)(bufD + cur * 16384                      \
                                      + ((J) - 1) * 1024 + 4 * pl);           \
            gbase[((size_t)ch * 16 + (J) - 1) * 256 + pl] = v;                \
            if ((J) >= 1 && (J) <= 8 && ch + 1 < NCH_) {                      \
                f16x8 a = *(const f16x8*)((const char*)Ax                     \
                                          + (vbaseA ^ (((J) - 1) * 64)));     \
                MFMA16(a, wf[(J) - 1][0], pacc0);                             \
                MFMA16(a, wf[(J) - 1][1], pacc1);                             \
                MFMA16(a, wf[(J) - 1][2], pacc2);                             \
                MFMA16(a, wf[(J) - 1][3], pacc3);                             \
            }                                                                 \
            if ((J) == 9 && ch + 1 < NCH_) {                                  \
                char* ob = bufD + (1 - cur) * 16384;                          \
                _Pragma("unroll") for (int r = 0; r < 4; ++r) {               \
                    float* row = (float*)(ob + (g * 4 + r) * 1024)            \
                                 + colbase + c;                               \
                    row[0]  = pacc0[r] + pbb0;  row[16] = pacc1[r] + pbb1;    \
                    row[32] = pacc2[r] + pbb2;  row[48] = pacc3[r] + pbb3;    \
                }                                                             \
                pacc0 = f32x4{0,0,0,0}; pacc1 = f32x4{0,0,0,0};               \
                pacc2 = f32x4{0,0,0,0}; pacc3 = f32x4{0,0,0,0};               \
            }                                                                 \
            if ((J) == 10 && ch + 2 < NCH_) {                                 \
                const float* gs = ibase + (size_t)(ch + 2) * CH_ * D_;        \
                p0 = *(const float4*)&gs[8 * pl];                             \
                p1 = *(const float4*)&gs[8 * pl + 4];                         \
                p2 = *(const float4*)&gs[8 * pl + 2048];                      \
                p3 = *(const float4*)&gs[8 * pl + 2052];                      \
            }                                                                 \
        }                                                                     \
        BAR()                                                                 \
    }

    int cur = 0;
    for (int ch = 0; ch < NCH_; ++ch) {
        if (scanw) {
            STEP(0)  STEP(1)  STEP(2)  STEP(3)
            STEP(4)  STEP(5)  STEP(6)  STEP(7)
            STEP(8)  STEP(9)  STEP(10) STEP(11)
            STEP(12) STEP(13) STEP(14) STEP(15)
        } else {
            SLICE(0)  SLICE(1)  SLICE(2)  SLICE(3)
            SLICE(4)  SLICE(5)  SLICE(6)  SLICE(7)
            SLICE(8)  SLICE(9)  SLICE(10) SLICE(11)
            SLICE(12) SLICE(13) SLICE(14) SLICE(15)
        }
        cur ^= 1;
    }
    // epilogue: dump row 15 of the last chunk (chunk 63 used buf[1])
    if (!scanw) {
        float v = *(const float*)(bufD + 16384 + 15 * 1024 + 4 * pl);
        gbase[(size_t)1023 * 256 + pl] = v;
    }
#undef STEP
#undef SLICE
#undef BAR
#undef MFMA16
#undef PACK8
}

// ---------------------------------------------------------------------------
extern "C" void kernel_launch(void* const* d_in, const int* in_sizes, int n_in,
                              void* d_out, int out_size, void* d_ws, size_t ws_size,
                              hipStream_t stream) {
    const float* inputs = (const float*)d_in[0];   // [B, T, D]
    const float* W_xh   = (const float*)d_in[1];   // [D, U]
    const float* W_hh   = (const float*)d_in[2];   // [U, U]
    const float* b_h    = (const float*)d_in[3];   // [U]
    float* out = (float*)d_out;                    // [B, T, U]

    rnn_fused<<<B_, NT2_, 0, stream>>>(inputs, W_xh, W_hh, b_h, out);
}

// Round 11
// 546.375 us; speedup vs baseline: 1.1903x; 1.1903x over previous
//
#include <hip/hip_runtime.h>
#include <math.h>

#define B_ 64
#define T_ 1024
#define D_ 256
#define U_ 256

typedef __fp16   hf2_t __attribute__((ext_vector_type(2)));  // cvt_pkrtz ret type
typedef _Float16 f16x8 __attribute__((ext_vector_type(8)));
typedef float    f32x4 __attribute__((ext_vector_type(4)));

// ---------------------------------------------------------------------------
// branch-free fast tanh: tanh(x) = 1 - 2/(1 + e^{2x}). (validated R2..R9)
// ---------------------------------------------------------------------------
__device__ __forceinline__ float fast_tanh2(float x) {
    float e = __expf(2.0f * x);
    return 1.0f - 2.0f * __builtin_amdgcn_rcpf(e + 1.0f);
}

// ---------------------------------------------------------------------------
// R10 = R8 (best, 499 us) minus measured per-step overheads. Homogeneous
// waves (R9's role split regressed: barrier skew = max over roles).
//  1. h stored to global DIRECTLY from registers in-step (every lane holds
//     its columns' h via D-replication). Deletes h->buf LDS writes, the
//     boundary dump phase, and one boundary barrier. buf = xw only.
//  2. Persistent zero4 C-init: chains start as mfma(a, w, zero4) instead of
//     8x f32x4 zero-movs per wave per step (~120 VALU cyc/SIMD/step).
//  3. s_setprio(1) around the MFMA cluster (T5).
// Math, fragment mappings, swizzle, PACK, PROJECT identical to R7/R8.
// (R10 bench was an infra timeout — this is the same kernel resubmitted.)
// ---------------------------------------------------------------------------
#define CH_  16
#define NCH_ (T_ / CH_)
#define NT2_ 512

__global__ __launch_bounds__(NT2_) __attribute__((amdgpu_waves_per_eu(2, 2)))
void rnn_fused(const float* __restrict__ inputs,  // [B_, T_, D_]
               const float* __restrict__ W_xh,    // [D_, U_]
               const float* __restrict__ W_hh,    // [U_, U_]
               const float* __restrict__ b_h,     // [U_]
               float* __restrict__ out) {         // [B_, T_, U_] h out
    const int b    = (int)blockIdx.x;
    const int tid  = (int)threadIdx.x;
    const int w    = tid >> 6;                  // wave 0..7: cols [32w, 32w+32)
    const int lane = tid & 63;
    const int g    = lane >> 4;                 // k/row group 0..3
    const int c    = lane & 15;                 // col within n-tile
    const int n0   = w * 32;

    __shared__ float xwb[2][CH_][U_];               // 32 KB xw (double-buffered)
    __shared__ __align__(16) _Float16 hl[2][U_];    // 2 x 512 B h state
    __shared__ __align__(16) _Float16 Ax[CH_ * D_]; // 8 KB inputs chunk (f16,swz)

    // resident B-fragments (validated mapping): frag[kt][nt] elem j =
    // W[kt*32 + g*8 + j][n0 + nt*16 + c]
    f16x8 whh[8][2], wxh[8][2];
    #pragma unroll
    for (int kt = 0; kt < 8; ++kt) {
        #pragma unroll
        for (int nt = 0; nt < 2; ++nt) {
            f16x8 vh, vx;
            #pragma unroll
            for (int j = 0; j < 8; ++j) {
                const int row = kt * 32 + g * 8 + j;
                const int col = n0 + nt * 16 + c;
                vh[j] = (_Float16)W_hh[(size_t)row * U_ + col];
                vx[j] = (_Float16)W_xh[(size_t)row * U_ + col];
            }
            whh[kt][nt] = vh;
            wxh[kt][nt] = vx;
        }
    }
    const float bb0 = b_h[n0 + c];
    const float bb1 = b_h[n0 + 16 + c];

    if (tid < 128) ((float*)&hl[0][0])[tid] = 0.f;   // zero h (512 B)

    const float* ibase = inputs + (size_t)b * T_ * D_;
    float* gbase = out + (size_t)b * T_ * U_;

    // Ax staging address (R7-validated swizzle)
    const int srow = tid >> 5;
    const int sk8  = (tid & 31) * 8;
    char* const sdst = (char*)Ax + srow * 512 + ((sk8 * 2) ^ ((srow & 7) << 4));
    // Ax fragment read base
    const int vbaseA = c * 512 + ((g * 16) ^ ((c & 7) << 4));

    const f32x4 zero4 = {0.f, 0.f, 0.f, 0.f};   // persistent C-init

#define PACK8(DST, F0, F1)                                                    \
    {                                                                         \
        union { hf2_t p[4]; f16x8 v; } u;                                     \
        u.p[0] = __builtin_amdgcn_cvt_pkrtz((F0).x, (F0).y);                  \
        u.p[1] = __builtin_amdgcn_cvt_pkrtz((F0).z, (F0).w);                  \
        u.p[2] = __builtin_amdgcn_cvt_pkrtz((F1).x, (F1).y);                  \
        u.p[3] = __builtin_amdgcn_cvt_pkrtz((F1).z, (F1).w);                  \
        *(f16x8*)(DST) = u.v;                                                 \
    }

#define MFMA16(A, BF, ACC) \
    ACC = __builtin_amdgcn_mfma_f32_16x16x32_f16((A), (BF), (ACC), 0, 0, 0)

#define BAR()                                                                 \
    asm volatile("s_waitcnt lgkmcnt(0)" ::: "memory");                        \
    __builtin_amdgcn_s_barrier();                                             \
    asm volatile("" ::: "memory");

    // projection: xw chunk = Ax @ W_xh + b -> xwb[PB] (split 4-deep chains)
#define PROJECT(PB)                                                           \
    {                                                                         \
        f16x8 a0_ = *(const f16x8*)((const char*)Ax + (vbaseA ^ 0));          \
        f32x4 q0 = zero4, q1 = zero4, q2 = zero4, q3 = zero4;                 \
        MFMA16(a0_, wxh[0][0], q0); MFMA16(a0_, wxh[0][1], q1);               \
        _Pragma("unroll") for (int kt = 1; kt < 4; ++kt) {                    \
            f16x8 a = *(const f16x8*)((const char*)Ax + (vbaseA ^ (kt * 64)));\
            MFMA16(a, wxh[kt][0], q0); MFMA16(a, wxh[kt][1], q1);             \
        }                                                                     \
        _Pragma("unroll") for (int kt = 4; kt < 8; ++kt) {                    \
            f16x8 a = *(const f16x8*)((const char*)Ax + (vbaseA ^ (kt * 64)));\
            MFMA16(a, wxh[kt][0], q2); MFMA16(a, wxh[kt][1], q3);             \
        }                                                                     \
        _Pragma("unroll") for (int r = 0; r < 4; ++r) {                       \
            xwb[PB][g * 4 + r][n0 + c]      = q0[r] + q2[r] + bb0;            \
            xwb[PB][g * 4 + r][n0 + 16 + c] = q1[r] + q3[r] + bb1;            \
        }                                                                     \
    }

    // ---- prologue: stage inputs chunk 0, project -> xwb[0], prefetch ch 1
    {
        float4 f0 = *(const float4*)&ibase[8 * tid];
        float4 f1 = *(const float4*)&ibase[8 * tid + 4];
        PACK8(sdst, f0, f1)
    }
    __syncthreads();
    PROJECT(0)
    float4 p0, p1;
    {
        const float* gs = ibase + (size_t)CH_ * D_;
        p0 = *(const float4*)&gs[8 * tid];
        p1 = *(const float4*)&gs[8 * tid + 4];
    }
    BAR()

    // scan-wave lane addresses
    const char* hrd = (const char*)&hl[0][0] + g * 16;   // A-read (+64*kt)
    char*       hwr = (char*)&hl[0][0] + (n0 + c) * 2;   // h-write (+32 for nt1)

    // step J: reads hl[J&1] + xwb[cur] row J; writes hl[(J&1)^1]; h -> global
#define STEP(J)                                                               \
    {                                                                         \
        const int RD = ((J) & 1) * 512;                                       \
        const int WR = 512 - RD;                                              \
        const float* bcf = &xwb[cur][(J)][n0 + c];                            \
        const float xw0 = bcf[0];                                             \
        const float xw1 = bcf[16];                                            \
        __builtin_amdgcn_s_setprio(1);                                        \
        f16x8 af0 = *(const f16x8*)(hrd + RD);                                \
        f32x4 ca0 = zero4, ca1 = zero4, cb0 = zero4, cb1 = zero4;             \
        MFMA16(af0, whh[0][0], ca0); MFMA16(af0, whh[0][1], ca1);             \
        _Pragma("unroll") for (int kt = 1; kt < 4; ++kt) {                    \
            f16x8 a = *(const f16x8*)(hrd + RD + 64 * kt);                    \
            MFMA16(a, whh[kt][0], ca0); MFMA16(a, whh[kt][1], ca1);           \
        }                                                                     \
        _Pragma("unroll") for (int kt = 4; kt < 8; ++kt) {                    \
            f16x8 a = *(const f16x8*)(hrd + RD + 64 * kt);                    \
            MFMA16(a, whh[kt][0], cb0); MFMA16(a, whh[kt][1], cb1);           \
        }                                                                     \
        __builtin_amdgcn_s_setprio(0);                                        \
        const float h0 = fast_tanh2(ca0[0] + cb0[0] + xw0);                   \
        const float h1 = fast_tanh2(ca1[0] + cb1[0] + xw1);                   \
        if (g == 0) {                                                         \
            *(_Float16*)(hwr + WR)      = (_Float16)h0;                       \
            *(_Float16*)(hwr + WR + 32) = (_Float16)h1;                       \
            float* go = gbase + (size_t)(ch * CH_ + (J)) * U_ + n0 + c;       \
            go[0]  = h0;                                                      \
            go[16] = h1;                                                      \
        }                                                                     \
        BAR()                                                                 \
    }

    int cur = 0;
    for (int ch = 0; ch < NCH_; ++ch) {
        STEP(0)  STEP(1)  STEP(2)  STEP(3)
        STEP(4)  STEP(5)  STEP(6)  STEP(7)
        STEP(8)  STEP(9)  STEP(10) STEP(11)
        STEP(12) STEP(13) STEP(14) STEP(15)

        // ---- chunk boundary (no h dump needed: stores happened in-step) ---
        if (ch + 1 < NCH_) { PACK8(sdst, p0, p1) }
        BAR()                                   // Ax visible for PROJECT
        if (ch + 1 < NCH_) PROJECT(1 - cur)
        if (ch + 2 < NCH_) {
            const float* gs = ibase + (size_t)(ch + 2) * CH_ * D_;
            p0 = *(const float4*)&gs[8 * tid];
            p1 = *(const float4*)&gs[8 * tid + 4];
        }
        BAR()                                   // xwb[1-cur] visible
        cur ^= 1;
    }
#undef STEP
#undef PROJECT
#undef BAR
#undef MFMA16
#undef PACK8
}

// ---------------------------------------------------------------------------
extern "C" void kernel_launch(void* const* d_in, const int* in_sizes, int n_in,
                              void* d_out, int out_size, void* d_ws, size_t ws_size,
                              hipStream_t stream) {
    const float* inputs = (const float*)d_in[0];   // [B, T, D]
    const float* W_xh   = (const float*)d_in[1];   // [D, U]
    const float* W_hh   = (const float*)d_in[2];   // [U, U]
    const float* b_h    = (const float*)d_in[3];   // [U]
    float* out = (float*)d_out;                    // [B, T, U]

    rnn_fused<<<B_, NT2_, 0, stream>>>(inputs, W_xh, W_hh, b_h, out);
}

// Round 12
// 516.780 us; speedup vs baseline: 1.2585x; 1.0573x over previous
//
#include <hip/hip_runtime.h>
#include <math.h>

#define B_ 64
#define T_ 1024
#define D_ 256
#define U_ 256

typedef __fp16   hf2_t __attribute__((ext_vector_type(2)));  // cvt_pkrtz ret type
typedef _Float16 f16x8 __attribute__((ext_vector_type(8)));
typedef float    f32x4 __attribute__((ext_vector_type(4)));

// ---------------------------------------------------------------------------
// branch-free fast tanh: tanh(x) = 1 - 2/(1 + e^{2x}). (validated R2..R11)
// ---------------------------------------------------------------------------
__device__ __forceinline__ float fast_tanh2(float x) {
    float e = __expf(2.0f * x);
    return 1.0f - 2.0f * __builtin_amdgcn_rcpf(e + 1.0f);
}

// ---------------------------------------------------------------------------
// R12 = R11 (466 us) with the xW LDS round-trip deleted + column pairing.
//  1. xw lives in REGISTERS: PROJECT's D rows (g*4+r) are exactly the rows
//     this lane's g-group needs at steps J=4g..4g+3. Rotating finalize:
//     step J finalized by g-group J>>2 using its own qa[J&3]/qb[J&3]
//     (J compile-time -> static extract). Deletes xwb (32 KB), PROJECT's
//     LDS writes, per-step xw LDS reads, and one boundary barrier.
//  2. Column pairing: tile0 -> col n0+2c, tile1 -> col n0+2c+1 (a free
//     permutation of the B-fragment gather). Finalize cols are adjacent:
//     h LDS write packs to one b32, global store to one float2.
// A-broadcast reads, swizzle, PACK, MFMA mappings unchanged (validated).
// ---------------------------------------------------------------------------
#define CH_  16
#define NCH_ (T_ / CH_)
#define NT2_ 512

__global__ __launch_bounds__(NT2_) __attribute__((amdgpu_waves_per_eu(2, 2)))
void rnn_fused(const float* __restrict__ inputs,  // [B_, T_, D_]
               const float* __restrict__ W_xh,    // [D_, U_]
               const float* __restrict__ W_hh,    // [U_, U_]
               const float* __restrict__ b_h,     // [U_]
               float* __restrict__ out) {         // [B_, T_, U_] h out
    const int b    = (int)blockIdx.x;
    const int tid  = (int)threadIdx.x;
    const int w    = tid >> 6;                  // wave 0..7: cols [32w, 32w+32)
    const int lane = tid & 63;
    const int g    = lane >> 4;                 // k/row group 0..3
    const int c    = lane & 15;
    const int n0   = w * 32;
    const int cp   = n0 + 2 * c;                // paired col base (tile0=cp, tile1=cp+1)

    __shared__ __align__(16) _Float16 hl[2][U_];    // 2 x 512 B h state
    __shared__ __align__(16) _Float16 Ax[CH_ * D_]; // 8 KB inputs chunk (f16,swz)

    // B-fragments, paired cols: frag[kt][nt] elem j = W[kt*32+g*8+j][cp+nt]
    f16x8 whh[8][2], wxh[8][2];
    #pragma unroll
    for (int kt = 0; kt < 8; ++kt) {
        #pragma unroll
        for (int nt = 0; nt < 2; ++nt) {
            f16x8 vh, vx;
            #pragma unroll
            for (int j = 0; j < 8; ++j) {
                const int row = kt * 32 + g * 8 + j;
                vh[j] = (_Float16)W_hh[(size_t)row * U_ + cp + nt];
                vx[j] = (_Float16)W_xh[(size_t)row * U_ + cp + nt];
            }
            whh[kt][nt] = vh;
            wxh[kt][nt] = vx;
        }
    }
    const float bb0 = b_h[cp];
    const float bb1 = b_h[cp + 1];

    if (tid < 128) ((float*)&hl[0][0])[tid] = 0.f;   // zero h (512 B)

    const float* ibase = inputs + (size_t)b * T_ * D_;
    float* gbase = out + (size_t)b * T_ * U_;

    // Ax staging address (validated swizzle)
    const int srow = tid >> 5;
    const int sk8  = (tid & 31) * 8;
    char* const sdst = (char*)Ax + srow * 512 + ((sk8 * 2) ^ ((srow & 7) << 4));
    const int vbaseA = c * 512 + ((g * 16) ^ ((c & 7) << 4));

    const f32x4 zero4 = {0.f, 0.f, 0.f, 0.f};

#define PACK8(DST, F0, F1)                                                    \
    {                                                                         \
        union { hf2_t p[4]; f16x8 v; } u;                                     \
        u.p[0] = __builtin_amdgcn_cvt_pkrtz((F0).x, (F0).y);                  \
        u.p[1] = __builtin_amdgcn_cvt_pkrtz((F0).z, (F0).w);                  \
        u.p[2] = __builtin_amdgcn_cvt_pkrtz((F1).x, (F1).y);                  \
        u.p[3] = __builtin_amdgcn_cvt_pkrtz((F1).z, (F1).w);                  \
        *(f16x8*)(DST) = u.v;                                                 \
    }

#define MFMA16(A, BF, ACC) \
    ACC = __builtin_amdgcn_mfma_f32_16x16x32_f16((A), (BF), (ACC), 0, 0, 0)

#define BAR()                                                                 \
    asm volatile("s_waitcnt lgkmcnt(0)" ::: "memory");                        \
    __builtin_amdgcn_s_barrier();                                             \
    asm volatile("" ::: "memory");

    // xw chunk registers: qa[r]=xw[row 4g+r][cp]+b, qb=col cp+1 (REGISTERS)
    f32x4 qa = zero4, qb = zero4;

#define PROJECT()                                                             \
    {                                                                         \
        f32x4 q0 = zero4, q1 = zero4, q2 = zero4, q3 = zero4;                 \
        _Pragma("unroll") for (int kt = 0; kt < 4; ++kt) {                    \
            f16x8 a = *(const f16x8*)((const char*)Ax + (vbaseA ^ (kt * 64)));\
            MFMA16(a, wxh[kt][0], q0); MFMA16(a, wxh[kt][1], q1);             \
        }                                                                     \
        _Pragma("unroll") for (int kt = 4; kt < 8; ++kt) {                    \
            f16x8 a = *(const f16x8*)((const char*)Ax + (vbaseA ^ (kt * 64)));\
            MFMA16(a, wxh[kt][0], q2); MFMA16(a, wxh[kt][1], q3);             \
        }                                                                     \
        _Pragma("unroll") for (int r = 0; r < 4; ++r) {                       \
            qa[r] = q0[r] + q2[r] + bb0;                                      \
            qb[r] = q1[r] + q3[r] + bb1;                                      \
        }                                                                     \
    }

    // ---- prologue: stage inputs chunk 0, project -> regs, prefetch chunk 1
    {
        float4 f0 = *(const float4*)&ibase[8 * tid];
        float4 f1 = *(const float4*)&ibase[8 * tid + 4];
        PACK8(sdst, f0, f1)
    }
    __syncthreads();
    PROJECT()
    float4 p0, p1;
    {
        const float* gs = ibase + (size_t)CH_ * D_;
        p0 = *(const float4*)&gs[8 * tid];
        p1 = *(const float4*)&gs[8 * tid + 4];
    }
    BAR()

    const char* hrd = (const char*)&hl[0][0] + g * 16;   // A-read (+64*kt)
    char*       hwr = (char*)&hl[0][0] + cp * 2;         // paired h-write (b32)

    // step J: reads hl[J&1]; g-group J>>2 finalizes with qa[J&3]/qb[J&3];
    // writes hl[(J&1)^1] (b32 pair) + global (float2)
#define STEP(J)                                                               \
    {                                                                         \
        const int RD = ((J) & 1) * 512;                                       \
        const int WR = 512 - RD;                                              \
        __builtin_amdgcn_s_setprio(1);                                        \
        f16x8 af0 = *(const f16x8*)(hrd + RD);                                \
        f32x4 ca0 = zero4, ca1 = zero4, cb0 = zero4, cb1 = zero4;             \
        MFMA16(af0, whh[0][0], ca0); MFMA16(af0, whh[0][1], ca1);             \
        _Pragma("unroll") for (int kt = 1; kt < 4; ++kt) {                    \
            f16x8 a = *(const f16x8*)(hrd + RD + 64 * kt);                    \
            MFMA16(a, whh[kt][0], ca0); MFMA16(a, whh[kt][1], ca1);           \
        }                                                                     \
        _Pragma("unroll") for (int kt = 4; kt < 8; ++kt) {                    \
            f16x8 a = *(const f16x8*)(hrd + RD + 64 * kt);                    \
            MFMA16(a, whh[kt][0], cb0); MFMA16(a, whh[kt][1], cb1);           \
        }                                                                     \
        __builtin_amdgcn_s_setprio(0);                                        \
        if (g == ((J) >> 2)) {                                                \
            const float h0 = fast_tanh2(ca0[0] + cb0[0] + qa[(J) & 3]);       \
            const float h1 = fast_tanh2(ca1[0] + cb1[0] + qb[(J) & 3]);       \
            *(hf2_t*)(hwr + WR) = __builtin_amdgcn_cvt_pkrtz(h0, h1);         \
            float* go = gbase + (size_t)(ch * CH_ + (J)) * U_ + cp;           \
            *(float2*)go = make_float2(h0, h1);                               \
        }                                                                     \
        BAR()                                                                 \
    }

    for (int ch = 0; ch < NCH_; ++ch) {
        STEP(0)  STEP(1)  STEP(2)  STEP(3)
        STEP(4)  STEP(5)  STEP(6)  STEP(7)
        STEP(8)  STEP(9)  STEP(10) STEP(11)
        STEP(12) STEP(13) STEP(14) STEP(15)

        // ---- chunk boundary: single barrier (xw handoff is in registers) --
        if (ch + 1 < NCH_) { PACK8(sdst, p0, p1) }
        BAR()                                   // Ax visible for PROJECT
        if (ch + 1 < NCH_) PROJECT()            // next chunk's xw -> qa/qb
        if (ch + 2 < NCH_) {
            const float* gs = ibase + (size_t)(ch + 2) * CH_ * D_;
            p0 = *(const float4*)&gs[8 * tid];
            p1 = *(const float4*)&gs[8 * tid + 4];
        }
        // no second barrier: next STEP(0)'s hl read is ordered by STEP(15)'s
        // barrier; PROJECT fed registers only.
    }
#undef STEP
#undef PROJECT
#undef BAR
#undef MFMA16
#undef PACK8
}

// ---------------------------------------------------------------------------
extern "C" void kernel_launch(void* const* d_in, const int* in_sizes, int n_in,
                              void* d_out, int out_size, void* d_ws, size_t ws_size,
                              hipStream_t stream) {
    const float* inputs = (const float*)d_in[0];   // [B, T, D]
    const float* W_xh   = (const float*)d_in[1];   // [D, U]
    const float* W_hh   = (const float*)d_in[2];   // [U, U]
    const float* b_h    = (const float*)d_in[3];   // [U]
    float* out = (float*)d_out;                    // [B, T, U]

    rnn_fused<<<B_, NT2_, 0, stream>>>(inputs, W_xh, W_hh, b_h, out);
}

// Round 13
// 513.510 us; speedup vs baseline: 1.2665x; 1.0064x over previous
//
#include <hip/hip_runtime.h>
#include <math.h>

#define B_ 64
#define T_ 1024
#define D_ 256
#define U_ 256

typedef __fp16   hf2_t __attribute__((ext_vector_type(2)));  // cvt_pkrtz ret type
typedef _Float16 f16x8 __attribute__((ext_vector_type(8)));
typedef float    f32x4 __attribute__((ext_vector_type(4)));

// ---------------------------------------------------------------------------
// branch-free fast tanh: tanh(x) = 1 - 2/(1 + e^{2x}). (validated R2..R12)
// ---------------------------------------------------------------------------
__device__ __forceinline__ float fast_tanh2(float x) {
    float e = __expf(2.0f * x);
    return 1.0f - 2.0f * __builtin_amdgcn_rcpf(e + 1.0f);
}

// ---------------------------------------------------------------------------
// R13 = R12 (440 us) with the chunk-boundary PROJECT bulge flattened and
// s_setprio removed (A/B: m190 measured setprio HURTING lockstep
// barrier-synced kernels; R10 bundled it with wins, never isolated).
//  * Ax pipelined one chunk ahead: during chunk ch, Ax = inputs[ch+1].
//    Steps 0..7 each absorb one Ax ds_read + 2 MFMA into qn accumulators
//    (off the critical path). Boundary = {qa<-qn+bias (regs), PACK, BAR,
//    prefetch}: the 16-MFMA+8-read bulge (~350 cyc/16 steps) disappears.
//  * xw summation order: one 8-deep chain (was 2x4 split) - f32 reorder
//    noise ~1e-6, invisible at absmax 0.0039.
// Everything else identical to R12 (validated).
// ---------------------------------------------------------------------------
#define CH_  16
#define NCH_ (T_ / CH_)
#define NT2_ 512

__global__ __launch_bounds__(NT2_) __attribute__((amdgpu_waves_per_eu(2, 2)))
void rnn_fused(const float* __restrict__ inputs,  // [B_, T_, D_]
               const float* __restrict__ W_xh,    // [D_, U_]
               const float* __restrict__ W_hh,    // [U_, U_]
               const float* __restrict__ b_h,     // [U_]
               float* __restrict__ out) {         // [B_, T_, U_] h out
    const int b    = (int)blockIdx.x;
    const int tid  = (int)threadIdx.x;
    const int w    = tid >> 6;                  // wave 0..7: cols [32w, 32w+32)
    const int lane = tid & 63;
    const int g    = lane >> 4;                 // k/row group 0..3
    const int c    = lane & 15;
    const int n0   = w * 32;
    const int cp   = n0 + 2 * c;                // paired col base

    __shared__ __align__(16) _Float16 hl[2][U_];    // 2 x 512 B h state
    __shared__ __align__(16) _Float16 Ax[CH_ * D_]; // 8 KB inputs chunk (f16,swz)

    // B-fragments, paired cols: frag[kt][nt] elem j = W[kt*32+g*8+j][cp+nt]
    f16x8 whh[8][2], wxh[8][2];
    #pragma unroll
    for (int kt = 0; kt < 8; ++kt) {
        #pragma unroll
        for (int nt = 0; nt < 2; ++nt) {
            f16x8 vh, vx;
            #pragma unroll
            for (int j = 0; j < 8; ++j) {
                const int row = kt * 32 + g * 8 + j;
                vh[j] = (_Float16)W_hh[(size_t)row * U_ + cp + nt];
                vx[j] = (_Float16)W_xh[(size_t)row * U_ + cp + nt];
            }
            whh[kt][nt] = vh;
            wxh[kt][nt] = vx;
        }
    }
    const float bb0 = b_h[cp];
    const float bb1 = b_h[cp + 1];

    if (tid < 128) ((float*)&hl[0][0])[tid] = 0.f;   // zero h (512 B)

    const float* ibase = inputs + (size_t)b * T_ * D_;
    float* gbase = out + (size_t)b * T_ * U_;

    // Ax staging address (validated swizzle)
    const int srow = tid >> 5;
    const int sk8  = (tid & 31) * 8;
    char* const sdst = (char*)Ax + srow * 512 + ((sk8 * 2) ^ ((srow & 7) << 4));
    const int vbaseA = c * 512 + ((g * 16) ^ ((c & 7) << 4));

    const f32x4 zero4 = {0.f, 0.f, 0.f, 0.f};

#define PACK8(DST, F0, F1)                                                    \
    {                                                                         \
        union { hf2_t p[4]; f16x8 v; } u;                                     \
        u.p[0] = __builtin_amdgcn_cvt_pkrtz((F0).x, (F0).y);                  \
        u.p[1] = __builtin_amdgcn_cvt_pkrtz((F0).z, (F0).w);                  \
        u.p[2] = __builtin_amdgcn_cvt_pkrtz((F1).x, (F1).y);                  \
        u.p[3] = __builtin_amdgcn_cvt_pkrtz((F1).z, (F1).w);                  \
        *(f16x8*)(DST) = u.v;                                                 \
    }

#define MFMA16(A, BF, ACC) \
    ACC = __builtin_amdgcn_mfma_f32_16x16x32_f16((A), (BF), (ACC), 0, 0, 0)

#define BAR()                                                                 \
    asm volatile("s_waitcnt lgkmcnt(0)" ::: "memory");                        \
    __builtin_amdgcn_s_barrier();                                             \
    asm volatile("" ::: "memory");

    // xw registers: qa/qb = current chunk's xw (+bias); qn = next chunk's
    // xw accumulating via the spread-project (one kt per step, steps 0..7).
    f32x4 qa = zero4, qb = zero4;
    f32x4 qn0 = zero4, qn1 = zero4;

    // ---- prologue -------------------------------------------------------
    // Ax <- inputs[0]; full PROJECT -> qa/qb (xw[0]); Ax <- inputs[1];
    // prefetch p <- inputs[2].
    {
        float4 f0 = *(const float4*)&ibase[8 * tid];
        float4 f1 = *(const float4*)&ibase[8 * tid + 4];
        PACK8(sdst, f0, f1)
    }
    __syncthreads();
    {
        f32x4 q0 = zero4, q1 = zero4, q2 = zero4, q3 = zero4;
        #pragma unroll
        for (int kt = 0; kt < 4; ++kt) {
            f16x8 a = *(const f16x8*)((const char*)Ax + (vbaseA ^ (kt * 64)));
            MFMA16(a, wxh[kt][0], q0); MFMA16(a, wxh[kt][1], q1);
        }
        #pragma unroll
        for (int kt = 4; kt < 8; ++kt) {
            f16x8 a = *(const f16x8*)((const char*)Ax + (vbaseA ^ (kt * 64)));
            MFMA16(a, wxh[kt][0], q2); MFMA16(a, wxh[kt][1], q3);
        }
        #pragma unroll
        for (int r = 0; r < 4; ++r) {
            qa[r] = q0[r] + q2[r] + bb0;
            qb[r] = q1[r] + q3[r] + bb1;
        }
    }
    BAR()                                   // protect Ax before overwrite
    {
        const float* gs = ibase + (size_t)CH_ * D_;
        float4 f0 = *(const float4*)&gs[8 * tid];
        float4 f1 = *(const float4*)&gs[8 * tid + 4];
        PACK8(sdst, f0, f1)                 // Ax <- inputs[1]
    }
    BAR()                                   // Ax[1] visible for spread reads
    float4 p0, p1;
    {
        const float* gs = ibase + (size_t)2 * CH_ * D_;
        p0 = *(const float4*)&gs[8 * tid];
        p1 = *(const float4*)&gs[8 * tid + 4];
    }

    const char* hrd = (const char*)&hl[0][0] + g * 16;   // A-read (+64*kt)
    char*       hwr = (char*)&hl[0][0] + cp * 2;         // paired h-write (b32)

    // step J: reads hl[J&1]; J<8 also spread-projects kt=J of next chunk's
    // xw from Ax; g-group J>>2 finalizes with qa[J&3]/qb[J&3]
#define STEP(J)                                                               \
    {                                                                         \
        const int RD = ((J) & 1) * 512;                                       \
        const int WR = 512 - RD;                                              \
        f16x8 af0 = *(const f16x8*)(hrd + RD);                                \
        f32x4 ca0 = zero4, ca1 = zero4, cb0 = zero4, cb1 = zero4;             \
        MFMA16(af0, whh[0][0], ca0); MFMA16(af0, whh[0][1], ca1);             \
        _Pragma("unroll") for (int kt = 1; kt < 4; ++kt) {                    \
            f16x8 a = *(const f16x8*)(hrd + RD + 64 * kt);                    \
            MFMA16(a, whh[kt][0], ca0); MFMA16(a, whh[kt][1], ca1);           \
        }                                                                     \
        _Pragma("unroll") for (int kt = 4; kt < 8; ++kt) {                    \
            f16x8 a = *(const f16x8*)(hrd + RD + 64 * kt);                    \
            MFMA16(a, whh[kt][0], cb0); MFMA16(a, whh[kt][1], cb1);           \
        }                                                                     \
        if ((J) < 8) {  /* spread-project: next chunk xw, kt = J */           \
            f16x8 ax = *(const f16x8*)((const char*)Ax + (vbaseA ^ ((J)*64)));\
            MFMA16(ax, wxh[(J)][0], qn0); MFMA16(ax, wxh[(J)][1], qn1);       \
        }                                                                     \
        if (g == ((J) >> 2)) {                                                \
            const float h0 = fast_tanh2(ca0[0] + cb0[0] + qa[(J) & 3]);       \
            const float h1 = fast_tanh2(ca1[0] + cb1[0] + qb[(J) & 3]);       \
            *(hf2_t*)(hwr + WR) = __builtin_amdgcn_cvt_pkrtz(h0, h1);         \
            float* go = gbase + (size_t)(ch * CH_ + (J)) * U_ + cp;           \
            *(float2*)go = make_float2(h0, h1);                               \
        }                                                                     \
        BAR()                                                                 \
    }

    for (int ch = 0; ch < NCH_; ++ch) {
        STEP(0)  STEP(1)  STEP(2)  STEP(3)
        STEP(4)  STEP(5)  STEP(6)  STEP(7)
        STEP(8)  STEP(9)  STEP(10) STEP(11)
        STEP(12) STEP(13) STEP(14) STEP(15)

        // ---- flat boundary: register handoff + PACK + one barrier --------
        #pragma unroll
        for (int r = 0; r < 4; ++r) {       // qa/qb <- next chunk's xw
            qa[r] = qn0[r] + bb0;
            qb[r] = qn1[r] + bb1;
        }
        qn0 = zero4; qn1 = zero4;
        if (ch + 2 < NCH_) { PACK8(sdst, p0, p1) }   // Ax <- inputs[ch+2]
        BAR()                                // Ax visible for next spread
        if (ch + 3 < NCH_) {                 // prefetch inputs[ch+3]
            const float* gs = ibase + (size_t)(ch + 3) * CH_ * D_;
            p0 = *(const float4*)&gs[8 * tid];
            p1 = *(const float4*)&gs[8 * tid + 4];
        }
    }
#undef STEP
#undef BAR
#undef MFMA16
#undef PACK8
}

// ---------------------------------------------------------------------------
extern "C" void kernel_launch(void* const* d_in, const int* in_sizes, int n_in,
                              void* d_out, int out_size, void* d_ws, size_t ws_size,
                              hipStream_t stream) {
    const float* inputs = (const float*)d_in[0];   // [B, T, D]
    const float* W_xh   = (const float*)d_in[1];   // [D, U]
    const float* W_hh   = (const float*)d_in[2];   // [U, U]
    const float* b_h    = (const float*)d_in[3];   // [U]
    float* out = (float*)d_out;                    // [B, T, U]

    rnn_fused<<<B_, NT2_, 0, stream>>>(inputs, W_xh, W_hh, b_h, out);
}